// Round 2
// baseline (965.859 us; speedup 1.0000x reference)
//
#include <hip/hip_runtime.h>
#include <hip/hip_bf16.h>
#include <stdint.h>

// Problem constants
#define NB 32
#define NS 512
#define ND 1024
#define NH 16
#define NDK 64
// M = NB*NS = 16384, K = ND = 1024, N = 3*ND = 3072

typedef unsigned short u16t;
typedef __bf16 bf16x8 __attribute__((ext_vector_type(8)));
typedef float f32x4 __attribute__((ext_vector_type(4)));
typedef u16t u16x8 __attribute__((ext_vector_type(8)));
typedef u16t u16x4 __attribute__((ext_vector_type(4)));

__device__ __forceinline__ u16t f2bf(float f) {
    uint32_t u = __float_as_uint(f);
    u += 0x7FFFu + ((u >> 16) & 1u);   // RNE
    return (u16t)(u >> 16);
}

// async global->LDS, 16B per lane. LDS dest must be wave-uniform base +
// lane*16 — caller guarantees the layout.
__device__ __forceinline__ void gload_lds16(const u16t* g, u16t* l) {
    __builtin_amdgcn_global_load_lds(
        (const __attribute__((address_space(1))) unsigned int*)g,
        (__attribute__((address_space(3))) unsigned int*)l, 16, 0, 0);
}

// ---------------------------------------------------------------------------
// Kernel 1: cast Q -> X (bf16), concat-cast Wq/Wk/Wv -> Wc (bf16 [3072][1024])
// ---------------------------------------------------------------------------
__global__ __launch_bounds__(256) void cast_kernel(
    const float4* __restrict__ Q, const float4* __restrict__ Wq,
    const float4* __restrict__ Wk, const float4* __restrict__ Wv,
    u16t* __restrict__ X, u16t* __restrict__ Wc)
{
    const int64_t NQ = 16777216 / 4;   // float4 groups in Q
    const int64_t NW = 1048576 / 4;    // float4 groups per W
    const int64_t total = NQ + 3 * NW;
    for (int64_t i = (int64_t)blockIdx.x * 256 + threadIdx.x; i < total;
         i += (int64_t)gridDim.x * 256) {
        float4 v;
        u16t* dst;
        if (i < NQ) {
            v = Q[i];
            dst = X + i * 4;
        } else {
            int64_t j = i - NQ;
            int sel = (int)(j / NW);
            int64_t t = j % NW;
            v = (sel == 0 ? Wq : sel == 1 ? Wk : Wv)[t];
            dst = Wc + (sel * NW + t) * 4;
        }
        u16x4 o;
        o.x = f2bf(v.x); o.y = f2bf(v.y); o.z = f2bf(v.z); o.w = f2bf(v.w);
        *(u16x4*)dst = o;
    }
}

// ---------------------------------------------------------------------------
// Kernel 2: QKV projection GEMM — 8-phase 256x256 schedule (T2+T3+T4+T5).
// C[m][n] = sum_k X[m][k] * Wc[n][k]  (+bias; q scaled 0.125; bf16 scatter).
//
// Geometry: BM=BN=256, BK=32, 512 threads = 8 waves (2M x 4N), per-wave
// output 128x64 = acc[8][4] f32x4. K = 1024 -> 32 K-tiles, 2 phases each
// (16 MFMA per phase: 4 mt x 4 nt).
//
// LDS: 4-deep ring per operand: A[4][256][32]bf16 (16KB/tile), B same ->
// 128 KiB total. Tile t lives in buf[t&3]; overwrite of buf[(t+3)&3] at
// tile t is safe (its tenant t-1 finished reads at t-1.ph2, drained by
// lgkmcnt + barrier).
//
// Chunk swizzle (T2, both-sides-or-neither, rule #21): logical 16B chunk
// (row, c) stored at LDS chunk (row, c ^ ((row>>1)&3)). gload_lds dest is
// LINEAR (chunk Lc=tid / tid+512 at offset Lc*16B); the SOURCE address is
// pre-inverse-swizzled (XOR is an involution). Frag reads apply the same
// XOR: since row = ...*16 + cl, (row>>1)&3 == (cl>>1)&3 (mt/nt terms are
// multiples of 8) -> per-thread constant. Bank quad = ((row&1)<<2)|(c^..)
// walks all 8 quads over 8 consecutive rows -> 2 lanes/quad = 2-way = free.
//
// Counted vmcnt (T4): issue schedule — tile t.ph1 issues A(t+3) (2 loads/
// thread), t.ph2 issues B(t+3). At each tile end, outstanding (oldest
// first) = A(t+1),B(t+1),A(t+2),B(t+2),A(t+3),B(t+3) = 12; vmcnt(8) drains
// exactly next tile's A+B. Tail keeps the count uniform by issuing dummy
// loads (clamped src X+tid*8, dest = dead ring slot). Prologue issues
// A0,B0,A1,B1,A2,B2 then vmcnt(8)+barrier. Raw s_barrier only — never
// __syncthreads (it would drain vmcnt to 0 and kill the pipeline).
// ---------------------------------------------------------------------------
#define MF(m_, a_, n_, b_) \
    acc[m_][n_] = __builtin_amdgcn_mfma_f32_16x16x32_bf16(a_, b_, acc[m_][n_], 0, 0, 0)

__global__ __launch_bounds__(512, 2) void gemm_qkv(
    const u16t* __restrict__ X, const u16t* __restrict__ Wc,
    const float* __restrict__ bq, const float* __restrict__ bk,
    const float* __restrict__ bv,
    u16t* __restrict__ Qp, u16t* __restrict__ Kp, u16t* __restrict__ Vp)
{
    __shared__ __align__(16) u16t sm[65536];   // 128 KiB: A ring [0,32768), B ring [32768,65536)
    const int tid = threadIdx.x;
    const int lane = tid & 63, wave = tid >> 6;
    const int cl = lane & 15, g4 = lane >> 4;
    const int wmRow = (wave >> 2) * 128;   // 2 M-waves
    const int wnCol = (wave & 3) * 64;     // 4 N-waves

    // XCD-aware swizzle: 768 blocks, 768%8==0 -> bijective. Per XCD: 8
    // contiguous bx strips, each reused across all 12 by (A panel L2-hot).
    const int bid = blockIdx.x;
    const int swz = (bid & 7) * 96 + (bid >> 3);
    const int bx = swz / 12, by = swz % 12;
    const int m0 = bx * 256, n0 = by * 256;

    f32x4 acc[8][4] = {};

    // ---- staging addresses (per thread: chunks Lc = tid and tid+512) ----
    const int row0 = tid >> 2;                       // 0..127
    const int csw  = (tid & 3) ^ ((tid >> 3) & 3);   // logical k-chunk for this slot
    const u16t* pA0 = X  + (size_t)(m0 + row0) * 1024 + csw * 8;
    const u16t* pA1 = pA0 + 128 * 1024;
    const u16t* pB0 = Wc + (size_t)(n0 + row0) * 1024 + csw * 8;
    const u16t* pB1 = pB0 + 128 * 1024;
    const u16t* Xd  = X + tid * 8;                   // dummy (tail) source

    // ---- fragment read offsets (u16 units), swizzle XOR folded in ----
    const int axor = (g4 ^ ((cl >> 1) & 3)) * 8;
    const int aoff = (wmRow + cl) * 32 + axor;            // + mt*512 + ring
    const int boff = 32768 + (wnCol + cl) * 32 + axor;    // + nt*512 + ring

    // ---- prologue: stage tiles 0,1,2 (order A,B per tile), wait to 8 ----
#pragma unroll
    for (int p = 0; p < 3; ++p) {
        gload_lds16(pA0 + p * 32, &sm[p * 8192 + tid * 8]);
        gload_lds16(pA1 + p * 32, &sm[p * 8192 + 4096 + tid * 8]);
        gload_lds16(pB0 + p * 32, &sm[32768 + p * 8192 + tid * 8]);
        gload_lds16(pB1 + p * 32, &sm[32768 + p * 8192 + 4096 + tid * 8]);
    }
    asm volatile("s_waitcnt vmcnt(8)\n\ts_barrier" ::: "memory");

    for (int t = 0; t < 32; ++t) {
        const int base = (t & 3) * 8192;
        const int tau = t + 3;
        const bool real = tau < 32;
        const int tb = (tau & 3) * 8192;

        // ================= phase 1: mt 0..3 =================
        const bf16x8 a0 = *(const bf16x8*)&sm[base + aoff];
        const bf16x8 a1 = *(const bf16x8*)&sm[base + aoff + 512];
        const bf16x8 a2 = *(const bf16x8*)&sm[base + aoff + 1024];
        const bf16x8 a3 = *(const bf16x8*)&sm[base + aoff + 1536];
        const bf16x8 b0 = *(const bf16x8*)&sm[base + boff];
        const bf16x8 b1 = *(const bf16x8*)&sm[base + boff + 512];
        const bf16x8 b2 = *(const bf16x8*)&sm[base + boff + 1024];
        const bf16x8 b3 = *(const bf16x8*)&sm[base + boff + 1536];
        {   // stage A(t+3) into its ring slot (tenant t-1 is done with it)
            const u16t* s0 = real ? pA0 + tau * 32 : Xd;
            const u16t* s1 = real ? pA1 + tau * 32 : Xd;
            gload_lds16(s0, &sm[tb + tid * 8]);
            gload_lds16(s1, &sm[tb + 4096 + tid * 8]);
        }
        asm volatile("s_barrier" ::: "memory");
        __builtin_amdgcn_s_setprio(1);
        MF(0, a0, 0, b0); MF(0, a0, 1, b1); MF(0, a0, 2, b2); MF(0, a0, 3, b3);
        MF(1, a1, 0, b0); MF(1, a1, 1, b1); MF(1, a1, 2, b2); MF(1, a1, 3, b3);
        MF(2, a2, 0, b0); MF(2, a2, 1, b1); MF(2, a2, 2, b2); MF(2, a2, 3, b3);
        MF(3, a3, 0, b0); MF(3, a3, 1, b1); MF(3, a3, 2, b2); MF(3, a3, 3, b3);
        __builtin_amdgcn_s_setprio(0);
        asm volatile("s_barrier" ::: "memory");

        // ================= phase 2: mt 4..7 (B frags reused) =================
        const bf16x8 a4 = *(const bf16x8*)&sm[base + aoff + 2048];
        const bf16x8 a5 = *(const bf16x8*)&sm[base + aoff + 2560];
        const bf16x8 a6 = *(const bf16x8*)&sm[base + aoff + 3072];
        const bf16x8 a7 = *(const bf16x8*)&sm[base + aoff + 3584];
        {   // stage B(t+3)
            const u16t* s0 = real ? pB0 + tau * 32 : Xd;
            const u16t* s1 = real ? pB1 + tau * 32 : Xd;
            gload_lds16(s0, &sm[32768 + tb + tid * 8]);
            gload_lds16(s1, &sm[32768 + tb + 4096 + tid * 8]);
        }
        asm volatile("s_barrier" ::: "memory");
        __builtin_amdgcn_s_setprio(1);
        MF(4, a4, 0, b0); MF(4, a4, 1, b1); MF(4, a4, 2, b2); MF(4, a4, 3, b3);
        MF(5, a5, 0, b0); MF(5, a5, 1, b1); MF(5, a5, 2, b2); MF(5, a5, 3, b3);
        MF(6, a6, 0, b0); MF(6, a6, 1, b1); MF(6, a6, 2, b2); MF(6, a6, 3, b3);
        MF(7, a7, 0, b0); MF(7, a7, 1, b1); MF(7, a7, 2, b2); MF(7, a7, 3, b3);
        __builtin_amdgcn_s_setprio(0);
        // counted wait: drains exactly A(t+1),B(t+1); 8 loads stay in flight
        asm volatile("s_waitcnt vmcnt(8)\n\ts_barrier" ::: "memory");
    }

    // ---- epilogue: +bias, q scale, bf16 scatter to [B,H,S,DK] ----
    const int w = n0 >> 10;  // 0:q 1:k 2:v (uniform: by 0-3 / 4-7 / 8-11)
    const float* bias = (w == 0) ? bq : (w == 1) ? bk : bv;
    u16t* outp = (w == 0) ? Qp : (w == 1) ? Kp : Vp;
    const float scale = (w == 0) ? 0.125f : 1.0f;
    const int nfbase = (n0 & 1023) + wnCol;
#pragma unroll
    for (int nt = 0; nt < 4; ++nt) {
        const int nf = nfbase + nt * 16 + cl;   // feature 0..1023
        const int h = nf >> 6, dk = nf & 63;
        const float bval = bias[nf];
#pragma unroll
        for (int mt = 0; mt < 8; ++mt) {
#pragma unroll
            for (int r = 0; r < 4; ++r) {
                const int m = m0 + wmRow + mt * 16 + g4 * 4 + r;
                const int b = m >> 9, s = m & 511;
                float val = (acc[mt][nt][r] + bval) * scale;
                outp[((size_t)(b * NH + h) * NS + s) * NDK + dk] = f2bf(val);
            }
        }
    }
}

// ---------------------------------------------------------------------------
// Kernel 3: transpose V [B,H,S,DK] -> Vt [B,H,DK,S] (bf16), LDS-tiled 64x64
// ---------------------------------------------------------------------------
__global__ __launch_bounds__(256) void transpose_v(
    const u16t* __restrict__ Vp, u16t* __restrict__ Vt)
{
    __shared__ __align__(16) u16t T[64 * 72];
    const int bh = blockIdx.x;   // 0..511
    const int sc = blockIdx.y;   // 0..7  (64-row chunk of S)
    const u16t* src = Vp + (size_t)bh * NS * NDK + (size_t)sc * 64 * NDK;
    u16t* dst = Vt + (size_t)bh * NDK * NS + sc * 64;

#pragma unroll
    for (int i = 0; i < 2; ++i) {
        int c = threadIdx.x + i * 256;       // 0..511
        int row = c >> 3, sg = c & 7;
        *(u16x8*)&T[row * 72 + sg * 8] = *(const u16x8*)&src[row * 64 + sg * 8];
    }
    __syncthreads();
#pragma unroll
    for (int i = 0; i < 2; ++i) {
        int c = threadIdx.x + i * 256;
        int dk = c >> 3, sg = c & 7;
        u16x8 v;
#pragma unroll
        for (int j = 0; j < 8; ++j) v[j] = T[(sg * 8 + j) * 72 + dk];
        *(u16x8*)&dst[(size_t)dk * NS + sg * 8] = v;
    }
}

// ---------------------------------------------------------------------------
// Kernel 4: fused attention per (b, h, 64 q-rows). Wave owns 16 q rows.
// Pass 1: E[kt] = exp(q.k) masked, kept in 128 VGPRs; row sums via shfl_xor.
// Pass 2: normalize -> write attn; P->LDS->A-frag; PV MFMA with Vt B-frags.
// Pst is per-wave private => NO __syncthreads needed (intra-wave LDS RAW is
// ordered by compiler-inserted lgkmcnt waits).
//
// R1: XCD-pin remap (8 qt-blocks of one bh share an XCD); wave-uniform
// length-skip; vectorized zero tail for masked attn columns.
// ---------------------------------------------------------------------------
__global__ __launch_bounds__(256) void attn_kernel(
    const u16t* __restrict__ Qp, const u16t* __restrict__ Kp,
    const u16t* __restrict__ Vt, const int* __restrict__ length,
    float* __restrict__ ctx, float* __restrict__ attn)
{
    __shared__ __align__(16) u16t Pst[4][16 * 40];  // per-wave, row stride 40
    const int tid = threadIdx.x, lane = tid & 63, wave = tid >> 6;
    const int cl = lane & 15, g4 = lane >> 4;
    const int raw = blockIdx.x;          // 0..4095
    const int bh = ((raw >> 6) << 3) | (raw & 7);  // XCD-pinned: bh%8 == raw%8
    const int qt = (raw >> 3) & 7;
    const int b = bh >> 4;
    const int len = length[b];
    const int nkt = (len + 15) >> 4;     // valid 16-key groups, 1..32
    const int ng  = (len + 31) >> 5;     // valid 32-key groups, 1..16
    const int qbase = qt * 64 + wave * 16;

    const u16t* qptr = Qp + (size_t)bh * NS * NDK + (size_t)qbase * NDK;
    const u16t* kptr = Kp + (size_t)bh * NS * NDK;
    const u16t* vtptr = Vt + (size_t)bh * NDK * NS;

    // Q A-frags (dk 0..31 and 32..63); q already scaled by 1/8
    const bf16x8 aq0 = *(const bf16x8*)&qptr[cl * 64 + g4 * 8];
    const bf16x8 aq1 = *(const bf16x8*)&qptr[cl * 64 + 32 + g4 * 8];

    f32x4 E[32];
    float rs[4] = {0.f, 0.f, 0.f, 0.f};
#pragma unroll
    for (int kt = 0; kt < 32; ++kt) {
        if (kt < nkt) {                  // wave-uniform (len uniform in block)
            const bf16x8 bk0 = *(const bf16x8*)&kptr[(kt * 16 + cl) * 64 + g4 * 8];
            const bf16x8 bk1 = *(const bf16x8*)&kptr[(kt * 16 + cl) * 64 + 32 + g4 * 8];
            f32x4 sc = {0.f, 0.f, 0.f, 0.f};
            sc = __builtin_amdgcn_mfma_f32_16x16x32_bf16(aq0, bk0, sc, 0, 0, 0);
            sc = __builtin_amdgcn_mfma_f32_16x16x32_bf16(aq1, bk1, sc, 0, 0, 0);
            const bool valid = (kt * 16 + cl) < len;   // C layout: col = lane&15
            f32x4 e;
#pragma unroll
            for (int r = 0; r < 4; ++r) {
                float ev = valid ? __expf(sc[r]) : 0.0f;
                e[r] = ev;
                rs[r] += ev;
            }
            E[kt] = e;
        } else {
            E[kt] = (f32x4){0.f, 0.f, 0.f, 0.f};
        }
    }

    // row-sum reduce across the 16 lanes sharing a row group (low 4 lane bits)
#pragma unroll
    for (int r = 0; r < 4; ++r) {
        float v = rs[r];
        v += __shfl_xor(v, 1);
        v += __shfl_xor(v, 2);
        v += __shfl_xor(v, 4);
        v += __shfl_xor(v, 8);
        rs[r] = 1.0f / (v + 1e-8f);
    }

    f32x4 cacc[4] = {};
    float* attnw = attn + ((size_t)bh * NS + qbase) * NS;
#pragma unroll
    for (int g = 0; g < 16; ++g) {       // 32-key groups
        if (g < ng) {                    // wave-uniform guard
#pragma unroll
            for (int t = 0; t < 2; ++t) {
                const int kt = g * 2 + t;
#pragma unroll
                for (int r = 0; r < 4; ++r) {
                    const float a = E[kt][r] * rs[r];
                    attnw[(size_t)(g4 * 4 + r) * NS + kt * 16 + cl] = a;
                    Pst[wave][(g4 * 4 + r) * 40 + t * 16 + cl] = f2bf(a);
                }
            }
            // P A-frag: rows=q (lane&15), k=key offset g4*8..+8 within the 32
            const bf16x8 ap = *(const bf16x8*)&Pst[wave][cl * 40 + g4 * 8];
#pragma unroll
            for (int nt = 0; nt < 4; ++nt) {
                const bf16x8 bv = *(const bf16x8*)
                    &vtptr[(size_t)(nt * 16 + cl) * NS + g * 32 + g4 * 8];
                cacc[nt] = __builtin_amdgcn_mfma_f32_16x16x32_bf16(
                    ap, bv, cacc[nt], 0, 0, 0);
            }
        }
    }

    // zero tail of attn (cols >= ng*32 are exactly 0 after masking+normalize)
    {
        const int zr = lane >> 2;            // 16 rows per wave
        const int zc = (lane & 3) * 4;       // 4 float4 lanes per row
        const float4 z = {0.f, 0.f, 0.f, 0.f};
        for (int c = ng * 32; c < NS; c += 16)
            *(float4*)&attnw[(size_t)zr * NS + c + zc] = z;
    }

    // context write: [b, s, h*64+dk]
    float* cw = ctx + ((size_t)b * NS + qbase) * ND + (bh & 15) * NDK;
#pragma unroll
    for (int nt = 0; nt < 4; ++nt)
#pragma unroll
        for (int r = 0; r < 4; ++r)
            cw[(size_t)(g4 * 4 + r) * ND + nt * 16 + cl] = cacc[nt][r];
}

// ---------------------------------------------------------------------------
extern "C" void kernel_launch(void* const* d_in, const int* in_sizes, int n_in,
                              void* d_out, int out_size, void* d_ws, size_t ws_size,
                              hipStream_t stream)
{
    const float* Q   = (const float*)d_in[0];
    const float* Wq  = (const float*)d_in[1];
    const float* bq  = (const float*)d_in[2];
    const float* Wk  = (const float*)d_in[3];
    const float* bk  = (const float*)d_in[4];
    const float* Wv  = (const float*)d_in[5];
    const float* bv  = (const float*)d_in[6];
    const int* length = (const int*)d_in[7];

    float* ctx  = (float*)d_out;                     // 16,777,216 floats
    float* attn = (float*)d_out + 16777216;          // 134,217,728 floats

    char* ws = (char*)d_ws;
    const size_t szX  = 33554432;   // 16.8M bf16
    const size_t szW  = 6291456;    // 3.1M bf16
    const size_t szP  = 33554432;   // each of Qp/Kp/Vp/Vt

    u16t *X, *Wc, *Qp, *Kp, *Vp, *Vt;
    const size_t needA = szX + szW + 4 * szP;        // ~174 MB
    if (ws_size >= needA) {
        X  = (u16t*)(ws);
        Wc = (u16t*)(ws + szX);
        Qp = (u16t*)(ws + szX + szW);
        Kp = (u16t*)(ws + szX + szW + szP);
        Vp = (u16t*)(ws + szX + szW + 2 * szP);
        Vt = (u16t*)(ws + szX + szW + 3 * szP);
    } else {
        // fallback: stage X/Wc in the attn output region (dead before attn
        // kernel runs); qkv buffers in ws (needs ~134 MB)
        X  = (u16t*)(attn);
        Wc = (u16t*)((char*)attn + szX);
        Qp = (u16t*)(ws);
        Kp = (u16t*)(ws + szP);
        Vp = (u16t*)(ws + 2 * szP);
        Vt = (u16t*)(ws + 3 * szP);
    }

    cast_kernel<<<dim3(2048), dim3(256), 0, stream>>>(
        (const float4*)Q, (const float4*)Wq, (const float4*)Wk,
        (const float4*)Wv, X, Wc);

    gemm_qkv<<<dim3(768), dim3(512), 0, stream>>>(
        X, Wc, bq, bk, bv, Qp, Kp, Vp);

    transpose_v<<<dim3(512, 8), dim3(256), 0, stream>>>(Vp, Vt);

    attn_kernel<<<dim3(4096), dim3(256), 0, stream>>>(
        Qp, Kp, Vt, length, ctx, attn);
}

// Round 3
// 963.453 us; speedup vs baseline: 1.0025x; 1.0025x over previous
//
#include <hip/hip_runtime.h>
#include <hip/hip_bf16.h>
#include <stdint.h>

// Problem constants
#define NB 32
#define NS 512
#define ND 1024
#define NH 16
#define NDK 64
// M = NB*NS = 16384, K = ND = 1024, N = 3*ND = 3072

typedef unsigned short u16t;
typedef __bf16 bf16x8 __attribute__((ext_vector_type(8)));
typedef float f32x4 __attribute__((ext_vector_type(4)));
typedef u16t u16x8 __attribute__((ext_vector_type(8)));
typedef u16t u16x4 __attribute__((ext_vector_type(4)));

__device__ __forceinline__ u16t f2bf(float f) {
    uint32_t u = __float_as_uint(f);
    u += 0x7FFFu + ((u >> 16) & 1u);   // RNE
    return (u16t)(u >> 16);
}

// async global->LDS, 16B per lane. LDS dest must be wave-uniform base +
// lane*16 — caller guarantees the layout.
__device__ __forceinline__ void gload_lds16(const u16t* g, u16t* l) {
    __builtin_amdgcn_global_load_lds(
        (const __attribute__((address_space(1))) unsigned int*)g,
        (__attribute__((address_space(3))) unsigned int*)l, 16, 0, 0);
}

// ---------------------------------------------------------------------------
// Kernel 1: cast Q -> X (bf16), concat-cast Wq/Wk/Wv -> Wc (bf16 [3072][1024])
// ---------------------------------------------------------------------------
__global__ __launch_bounds__(256) void cast_kernel(
    const float4* __restrict__ Q, const float4* __restrict__ Wq,
    const float4* __restrict__ Wk, const float4* __restrict__ Wv,
    u16t* __restrict__ X, u16t* __restrict__ Wc)
{
    const int64_t NQ = 16777216 / 4;   // float4 groups in Q
    const int64_t NW = 1048576 / 4;    // float4 groups per W
    const int64_t total = NQ + 3 * NW;
    for (int64_t i = (int64_t)blockIdx.x * 256 + threadIdx.x; i < total;
         i += (int64_t)gridDim.x * 256) {
        float4 v;
        u16t* dst;
        if (i < NQ) {
            v = Q[i];
            dst = X + i * 4;
        } else {
            int64_t j = i - NQ;
            int sel = (int)(j / NW);
            int64_t t = j % NW;
            v = (sel == 0 ? Wq : sel == 1 ? Wk : Wv)[t];
            dst = Wc + (sel * NW + t) * 4;
        }
        u16x4 o;
        o.x = f2bf(v.x); o.y = f2bf(v.y); o.z = f2bf(v.z); o.w = f2bf(v.w);
        *(u16x4*)dst = o;
    }
}

// ---------------------------------------------------------------------------
// Kernel 2: QKV projection GEMM. C[m][n] = sum_k X[m][k] * Wc[n][k]  (+bias)
// 128x128 tile, BK=32, 4 waves each 64x64 via 4x4 grid of 16x16x32 MFMA.
// (R3: reverted to the R1 m97-style structure — the 8-phase 256^2 port was
// neutral-to-negative here: K=1024 gives only 32 K-tiles and 128 KiB LDS
// forced 1 block/CU over a ragged 768-block tail.)
// ---------------------------------------------------------------------------
__global__ __launch_bounds__(256) void gemm_qkv(
    const u16t* __restrict__ X, const u16t* __restrict__ Wc,
    const float* __restrict__ bq, const float* __restrict__ bk,
    const float* __restrict__ bv,
    u16t* __restrict__ Qp, u16t* __restrict__ Kp, u16t* __restrict__ Vp)
{
    __shared__ __align__(16) u16t As[128 * 32];
    __shared__ __align__(16) u16t Bs[128 * 32];
    const int tid = threadIdx.x;
    const int lane = tid & 63, wave = tid >> 6;
    const int cl = lane & 15, g4 = lane >> 4;
    const int m0 = blockIdx.x * 128;
    const int n0 = blockIdx.y * 128;
    const int wm = (wave & 1) * 64, wn = (wave >> 1) * 64;

    f32x4 acc[4][4] = {};

    // staging: 512 16B segments per tile; thread owns segs tid and tid+256
    const int r0 = tid >> 2, sg0 = tid & 3;
    const int r1 = r0 + 64;
    const u16t* xrow0 = X  + (size_t)(m0 + r0) * 1024 + sg0 * 8;
    const u16t* xrow1 = X  + (size_t)(m0 + r1) * 1024 + sg0 * 8;
    const u16t* wrow0 = Wc + (size_t)(n0 + r0) * 1024 + sg0 * 8;
    const u16t* wrow1 = Wc + (size_t)(n0 + r1) * 1024 + sg0 * 8;
    u16t* asd0 = &As[r0 * 32 + sg0 * 8];
    u16t* asd1 = &As[r1 * 32 + sg0 * 8];
    u16t* bsd0 = &Bs[r0 * 32 + sg0 * 8];
    u16t* bsd1 = &Bs[r1 * 32 + sg0 * 8];

    for (int kt = 0; kt < 1024; kt += 32) {
        __syncthreads();
        gload_lds16(xrow0 + kt, asd0);
        gload_lds16(xrow1 + kt, asd1);
        gload_lds16(wrow0 + kt, bsd0);
        gload_lds16(wrow1 + kt, bsd1);
        __syncthreads();

        bf16x8 af[4], bf_[4];
#pragma unroll
        for (int t = 0; t < 4; ++t) {
            af[t]  = *(const bf16x8*)&As[(wm + t * 16 + cl) * 32 + g4 * 8];
            bf_[t] = *(const bf16x8*)&Bs[(wn + t * 16 + cl) * 32 + g4 * 8];
        }
#pragma unroll
        for (int mt = 0; mt < 4; ++mt)
#pragma unroll
            for (int nt = 0; nt < 4; ++nt)
                acc[mt][nt] = __builtin_amdgcn_mfma_f32_16x16x32_bf16(
                    af[mt], bf_[nt], acc[mt][nt], 0, 0, 0);
    }

    // epilogue
    const int w = n0 >> 10;  // 0:q 1:k 2:v (uniform per block: 128 | 1024)
    const float* bias = (w == 0) ? bq : (w == 1) ? bk : bv;
    u16t* outp = (w == 0) ? Qp : (w == 1) ? Kp : Vp;
    const float scale = (w == 0) ? 0.125f : 1.0f;
    const int nfbase = (n0 & 1023) + wn;
#pragma unroll
    for (int nt = 0; nt < 4; ++nt) {
        const int nf = nfbase + nt * 16 + cl;   // feature 0..1023
        const int h = nf >> 6, dk = nf & 63;
        const float bval = bias[nf];
#pragma unroll
        for (int mt = 0; mt < 4; ++mt) {
#pragma unroll
            for (int r = 0; r < 4; ++r) {
                const int m = m0 + wm + mt * 16 + g4 * 4 + r;
                const int b = m >> 9, s = m & 511;
                float val = (acc[mt][nt][r] + bval) * scale;
                outp[((size_t)(b * NH + h) * NS + s) * NDK + dk] = f2bf(val);
            }
        }
    }
}

// ---------------------------------------------------------------------------
// Kernel 3: transpose V [B,H,S,DK] -> Vt [B,H,DK,S] (bf16), LDS-tiled 64x64
// ---------------------------------------------------------------------------
__global__ __launch_bounds__(256) void transpose_v(
    const u16t* __restrict__ Vp, u16t* __restrict__ Vt)
{
    __shared__ __align__(16) u16t T[64 * 72];
    const int bh = blockIdx.x;   // 0..511
    const int sc = blockIdx.y;   // 0..7  (64-row chunk of S)
    const u16t* src = Vp + (size_t)bh * NS * NDK + (size_t)sc * 64 * NDK;
    u16t* dst = Vt + (size_t)bh * NDK * NS + sc * 64;

#pragma unroll
    for (int i = 0; i < 2; ++i) {
        int c = threadIdx.x + i * 256;       // 0..511
        int row = c >> 3, sg = c & 7;
        *(u16x8*)&T[row * 72 + sg * 8] = *(const u16x8*)&src[row * 64 + sg * 8];
    }
    __syncthreads();
#pragma unroll
    for (int i = 0; i < 2; ++i) {
        int c = threadIdx.x + i * 256;
        int dk = c >> 3, sg = c & 7;
        u16x8 v;
#pragma unroll
        for (int j = 0; j < 8; ++j) v[j] = T[(sg * 8 + j) * 72 + dk];
        *(u16x8*)&dst[(size_t)dk * NS + sg * 8] = v;
    }
}

// ---------------------------------------------------------------------------
// Kernel 4: fused attention per (b, h, 64 q-rows). Wave owns 16 q rows.
//
// R3 restructure: RECOMPUTE instead of caching scores. The old E[32] f32x4
// cache cost 128 VGPRs -> ~220 total -> ~2 waves/SIMD, leaving pass-1 K
// loads (L2 ~200cy) and pass-2 stores latency-exposed. Now:
//   Pass A: QK^T MFMA + exp, accumulate row sums only (scores discarded).
//   Pass B: recompute the SAME MFMA + exp (bit-identical), normalize,
//           write attn (f32), P->LDS->A-frag, PV MFMA.
// Extra cost: 64 MFMA/wave + dup exp (~5 us chip-wide). Benefit: ~90 VGPR
// -> ~5-6 waves/SIMD. Pass-B K reloads are L2-warm.
//
// Carried from R1: XCD-pin remap (8 qt-blocks of one bh share an XCD),
// wave-uniform length-skip, vectorized zero tail.
// ---------------------------------------------------------------------------
__global__ __launch_bounds__(256) void attn_kernel(
    const u16t* __restrict__ Qp, const u16t* __restrict__ Kp,
    const u16t* __restrict__ Vt, const int* __restrict__ length,
    float* __restrict__ ctx, float* __restrict__ attn)
{
    __shared__ __align__(16) u16t Pst[4][16 * 40];  // per-wave, row stride 40
    const int tid = threadIdx.x, lane = tid & 63, wave = tid >> 6;
    const int cl = lane & 15, g4 = lane >> 4;
    const int raw = blockIdx.x;          // 0..4095
    const int bh = ((raw >> 6) << 3) | (raw & 7);  // XCD-pinned: bh%8 == raw%8
    const int qt = (raw >> 3) & 7;
    const int b = bh >> 4;
    const int len = length[b];
    const int nkt = (len + 15) >> 4;     // valid 16-key groups, 1..32
    const int ng  = (len + 31) >> 5;     // valid 32-key groups, 1..16
    const int qbase = qt * 64 + wave * 16;

    const u16t* qptr = Qp + (size_t)bh * NS * NDK + (size_t)qbase * NDK;
    const u16t* kptr = Kp + (size_t)bh * NS * NDK;
    const u16t* vtptr = Vt + (size_t)bh * NDK * NS;

    // Q A-frags (dk 0..31 and 32..63); q already scaled by 1/8
    const bf16x8 aq0 = *(const bf16x8*)&qptr[cl * 64 + g4 * 8];
    const bf16x8 aq1 = *(const bf16x8*)&qptr[cl * 64 + 32 + g4 * 8];

    // ---- Pass A: row sums only ----
    float rs[4] = {0.f, 0.f, 0.f, 0.f};
#pragma unroll
    for (int kt = 0; kt < 32; ++kt) {
        if (kt < nkt) {                  // wave-uniform (len uniform in block)
            const bf16x8 bk0 = *(const bf16x8*)&kptr[(kt * 16 + cl) * 64 + g4 * 8];
            const bf16x8 bk1 = *(const bf16x8*)&kptr[(kt * 16 + cl) * 64 + 32 + g4 * 8];
            f32x4 sc = {0.f, 0.f, 0.f, 0.f};
            sc = __builtin_amdgcn_mfma_f32_16x16x32_bf16(aq0, bk0, sc, 0, 0, 0);
            sc = __builtin_amdgcn_mfma_f32_16x16x32_bf16(aq1, bk1, sc, 0, 0, 0);
            const bool valid = (kt * 16 + cl) < len;   // C layout: col = lane&15
#pragma unroll
            for (int r = 0; r < 4; ++r)
                rs[r] += valid ? __expf(sc[r]) : 0.0f;
        }
    }

    // row-sum reduce across the 16 lanes sharing a row group (low 4 lane bits)
#pragma unroll
    for (int r = 0; r < 4; ++r) {
        float v = rs[r];
        v += __shfl_xor(v, 1);
        v += __shfl_xor(v, 2);
        v += __shfl_xor(v, 4);
        v += __shfl_xor(v, 8);
        rs[r] = 1.0f / (v + 1e-8f);
    }

    // ---- Pass B: recompute scores, emit attn + P, PV MFMA ----
    f32x4 cacc[4] = {};
    float* attnw = attn + ((size_t)bh * NS + qbase) * NS;
#pragma unroll
    for (int g = 0; g < 16; ++g) {       // 32-key groups
        if (g < ng) {                    // wave-uniform guard
#pragma unroll
            for (int t = 0; t < 2; ++t) {
                const int kt = g * 2 + t;
                const bf16x8 bk0 = *(const bf16x8*)&kptr[(kt * 16 + cl) * 64 + g4 * 8];
                const bf16x8 bk1 = *(const bf16x8*)&kptr[(kt * 16 + cl) * 64 + 32 + g4 * 8];
                f32x4 sc = {0.f, 0.f, 0.f, 0.f};
                sc = __builtin_amdgcn_mfma_f32_16x16x32_bf16(aq0, bk0, sc, 0, 0, 0);
                sc = __builtin_amdgcn_mfma_f32_16x16x32_bf16(aq1, bk1, sc, 0, 0, 0);
                const bool valid = (kt * 16 + cl) < len;
#pragma unroll
                for (int r = 0; r < 4; ++r) {
                    const float e = valid ? __expf(sc[r]) : 0.0f;
                    const float a = e * rs[r];
                    attnw[(size_t)(g4 * 4 + r) * NS + kt * 16 + cl] = a;
                    Pst[wave][(g4 * 4 + r) * 40 + t * 16 + cl] = f2bf(a);
                }
            }
            // P A-frag: rows=q (lane&15), k=key offset g4*8..+8 within the 32
            const bf16x8 ap = *(const bf16x8*)&Pst[wave][cl * 40 + g4 * 8];
#pragma unroll
            for (int nt = 0; nt < 4; ++nt) {
                const bf16x8 bv = *(const bf16x8*)
                    &vtptr[(size_t)(nt * 16 + cl) * NS + g * 32 + g4 * 8];
                cacc[nt] = __builtin_amdgcn_mfma_f32_16x16x32_bf16(
                    ap, bv, cacc[nt], 0, 0, 0);
            }
        }
    }

    // zero tail of attn (cols >= ng*32 are exactly 0 after masking+normalize)
    {
        const int zr = lane >> 2;            // 16 rows per wave
        const int zc = (lane & 3) * 4;       // 4 float4 lanes per row
        const float4 z = {0.f, 0.f, 0.f, 0.f};
        for (int c = ng * 32; c < NS; c += 16)
            *(float4*)&attnw[(size_t)zr * NS + c + zc] = z;
    }

    // context write: [b, s, h*64+dk]
    float* cw = ctx + ((size_t)b * NS + qbase) * ND + (bh & 15) * NDK;
#pragma unroll
    for (int nt = 0; nt < 4; ++nt)
#pragma unroll
        for (int r = 0; r < 4; ++r)
            cw[(size_t)(g4 * 4 + r) * ND + nt * 16 + cl] = cacc[nt][r];
}

// ---------------------------------------------------------------------------
extern "C" void kernel_launch(void* const* d_in, const int* in_sizes, int n_in,
                              void* d_out, int out_size, void* d_ws, size_t ws_size,
                              hipStream_t stream)
{
    const float* Q   = (const float*)d_in[0];
    const float* Wq  = (const float*)d_in[1];
    const float* bq  = (const float*)d_in[2];
    const float* Wk  = (const float*)d_in[3];
    const float* bk  = (const float*)d_in[4];
    const float* Wv  = (const float*)d_in[5];
    const float* bv  = (const float*)d_in[6];
    const int* length = (const int*)d_in[7];

    float* ctx  = (float*)d_out;                     // 16,777,216 floats
    float* attn = (float*)d_out + 16777216;          // 134,217,728 floats

    char* ws = (char*)d_ws;
    const size_t szX  = 33554432;   // 16.8M bf16
    const size_t szW  = 6291456;    // 3.1M bf16
    const size_t szP  = 33554432;   // each of Qp/Kp/Vp/Vt

    u16t *X, *Wc, *Qp, *Kp, *Vp, *Vt;
    const size_t needA = szX + szW + 4 * szP;        // ~174 MB
    if (ws_size >= needA) {
        X  = (u16t*)(ws);
        Wc = (u16t*)(ws + szX);
        Qp = (u16t*)(ws + szX + szW);
        Kp = (u16t*)(ws + szX + szW + szP);
        Vp = (u16t*)(ws + szX + szW + 2 * szP);
        Vt = (u16t*)(ws + szX + szW + 3 * szP);
    } else {
        // fallback: stage X/Wc in the attn output region (dead before attn
        // kernel runs); qkv buffers in ws (needs ~134 MB)
        X  = (u16t*)(attn);
        Wc = (u16t*)((char*)attn + szX);
        Qp = (u16t*)(ws);
        Kp = (u16t*)(ws + szP);
        Vp = (u16t*)(ws + 2 * szP);
        Vt = (u16t*)(ws + 3 * szP);
    }

    cast_kernel<<<dim3(2048), dim3(256), 0, stream>>>(
        (const float4*)Q, (const float4*)Wq, (const float4*)Wk,
        (const float4*)Wv, X, Wc);

    gemm_qkv<<<dim3(128, 24), dim3(256), 0, stream>>>(
        X, Wc, bq, bk, bv, Qp, Kp, Vp);

    transpose_v<<<dim3(512, 8), dim3(256), 0, stream>>>(Vp, Vt);

    attn_kernel<<<dim3(4096), dim3(256), 0, stream>>>(
        Qp, Kp, Vt, length, ctx, attn);
}

// Round 4
// 957.030 us; speedup vs baseline: 1.0092x; 1.0067x over previous
//
#include <hip/hip_runtime.h>
#include <hip/hip_bf16.h>
#include <stdint.h>

// Problem constants
#define NB 32
#define NS 512
#define ND 1024
#define NH 16
#define NDK 64
// M = NB*NS = 16384, K = ND = 1024, N = 3*ND = 3072

typedef unsigned short u16t;
typedef __bf16 bf16x8 __attribute__((ext_vector_type(8)));
typedef float f32x4 __attribute__((ext_vector_type(4)));
typedef u16t u16x8 __attribute__((ext_vector_type(8)));
typedef u16t u16x4 __attribute__((ext_vector_type(4)));

__device__ __forceinline__ u16t f2bf(float f) {
    uint32_t u = __float_as_uint(f);
    u += 0x7FFFu + ((u >> 16) & 1u);   // RNE
    return (u16t)(u >> 16);
}

// async global->LDS, 16B per lane. LDS dest must be wave-uniform base +
// lane*16 — caller guarantees the layout.
__device__ __forceinline__ void gload_lds16(const u16t* g, u16t* l) {
    __builtin_amdgcn_global_load_lds(
        (const __attribute__((address_space(1))) unsigned int*)g,
        (__attribute__((address_space(3))) unsigned int*)l, 16, 0, 0);
}

// ---------------------------------------------------------------------------
// Kernel 1: cast Q -> X (bf16), concat-cast Wq/Wk/Wv -> Wc (bf16 [3072][1024])
// ---------------------------------------------------------------------------
__global__ __launch_bounds__(256) void cast_kernel(
    const float4* __restrict__ Q, const float4* __restrict__ Wq,
    const float4* __restrict__ Wk, const float4* __restrict__ Wv,
    u16t* __restrict__ X, u16t* __restrict__ Wc)
{
    const int64_t NQ = 16777216 / 4;   // float4 groups in Q
    const int64_t NW = 1048576 / 4;    // float4 groups per W
    const int64_t total = NQ + 3 * NW;
    for (int64_t i = (int64_t)blockIdx.x * 256 + threadIdx.x; i < total;
         i += (int64_t)gridDim.x * 256) {
        float4 v;
        u16t* dst;
        if (i < NQ) {
            v = Q[i];
            dst = X + i * 4;
        } else {
            int64_t j = i - NQ;
            int sel = (int)(j / NW);
            int64_t t = j % NW;
            v = (sel == 0 ? Wq : sel == 1 ? Wk : Wv)[t];
            dst = Wc + (sel * NW + t) * 4;
        }
        u16x4 o;
        o.x = f2bf(v.x); o.y = f2bf(v.y); o.z = f2bf(v.z); o.w = f2bf(v.w);
        *(u16x4*)dst = o;
    }
}

// ---------------------------------------------------------------------------
// Kernel 2: QKV projection GEMM. C[m][n] = sum_k X[m][k] * Wc[n][k]  (+bias)
// 128x128 tile, BK=32, 4 waves each 64x64 via 4x4 grid of 16x16x32 MFMA.
// Staging via global_load_lds width=16 (m97 recipe).
//
// R4: V-transpose FUSED into the epilogue. For w==2 blocks each wave's
// 64x64 acc tile is exactly one (b,h) x dk=0..63 x 64 consecutive s
// (nfbase is a multiple of 64), so the wave writes its tile into a
// per-wave LDS buffer [s_local][dk] (stride 72, overlaying the dead
// staging LDS after a barrier) and emits Vt[dk][s] rows as coalesced
// 128B u16x8 stores (transpose_v's proven gather pattern, now in-place).
// Kills the standalone transpose kernel (~64MB read + 64MB write + launch).
// ---------------------------------------------------------------------------
__global__ __launch_bounds__(256) void gemm_qkv(
    const u16t* __restrict__ X, const u16t* __restrict__ Wc,
    const float* __restrict__ bq, const float* __restrict__ bk,
    const float* __restrict__ bv,
    u16t* __restrict__ Qp, u16t* __restrict__ Kp, u16t* __restrict__ Vt)
{
    // overlay: staging As=[0,4096) u16, Bs=[4096,8192) u16 during K-loop;
    // after the K-loop the whole 18432-u16 (36.9KB) area becomes 4 per-wave
    // 64x72 transpose tiles (V blocks only).
    __shared__ __align__(16) u16t sm[18432];
    u16t* As = sm;
    u16t* Bs = sm + 4096;
    const int tid = threadIdx.x;
    const int lane = tid & 63, wave = tid >> 6;
    const int cl = lane & 15, g4 = lane >> 4;
    const int m0 = blockIdx.x * 128;
    const int n0 = blockIdx.y * 128;
    const int wm = (wave & 1) * 64, wn = (wave >> 1) * 64;

    f32x4 acc[4][4] = {};

    // staging: 512 16B segments per tile; thread owns segs tid and tid+256
    const int r0 = tid >> 2, sg0 = tid & 3;
    const int r1 = r0 + 64;
    const u16t* xrow0 = X  + (size_t)(m0 + r0) * 1024 + sg0 * 8;
    const u16t* xrow1 = X  + (size_t)(m0 + r1) * 1024 + sg0 * 8;
    const u16t* wrow0 = Wc + (size_t)(n0 + r0) * 1024 + sg0 * 8;
    const u16t* wrow1 = Wc + (size_t)(n0 + r1) * 1024 + sg0 * 8;
    u16t* asd0 = &As[r0 * 32 + sg0 * 8];
    u16t* asd1 = &As[r1 * 32 + sg0 * 8];
    u16t* bsd0 = &Bs[r0 * 32 + sg0 * 8];
    u16t* bsd1 = &Bs[r1 * 32 + sg0 * 8];

    for (int kt = 0; kt < 1024; kt += 32) {
        __syncthreads();
        gload_lds16(xrow0 + kt, asd0);
        gload_lds16(xrow1 + kt, asd1);
        gload_lds16(wrow0 + kt, bsd0);
        gload_lds16(wrow1 + kt, bsd1);
        __syncthreads();

        bf16x8 af[4], bf_[4];
#pragma unroll
        for (int t = 0; t < 4; ++t) {
            af[t]  = *(const bf16x8*)&As[(wm + t * 16 + cl) * 32 + g4 * 8];
            bf_[t] = *(const bf16x8*)&Bs[(wn + t * 16 + cl) * 32 + g4 * 8];
        }
#pragma unroll
        for (int mt = 0; mt < 4; ++mt)
#pragma unroll
            for (int nt = 0; nt < 4; ++nt)
                acc[mt][nt] = __builtin_amdgcn_mfma_f32_16x16x32_bf16(
                    af[mt], bf_[nt], acc[mt][nt], 0, 0, 0);
    }

    const int w = n0 >> 10;  // 0:q 1:k 2:v (uniform per block: 128 | 1024)
    const int nfbase = (n0 & 1023) + wn;   // multiple of 64 -> single head/wave

    if (w == 2) {
        // ---- fused V epilogue: bias add, LDS transpose, Vt[dk][s] store ----
        __syncthreads();                    // staging LDS is now dead
        u16t* T = &sm[wave * 4608];         // 64 x 72 per-wave tile
#pragma unroll
        for (int nt = 0; nt < 4; ++nt) {
            const int dk = nt * 16 + cl;
            const float bval = bv[nfbase + dk];
#pragma unroll
            for (int mt = 0; mt < 4; ++mt)
#pragma unroll
                for (int r = 0; r < 4; ++r)
                    T[(mt * 16 + g4 * 4 + r) * 72 + dk] =
                        f2bf(acc[mt][nt][r] + bval);
        }
        // intra-wave LDS RAW ordered by compiler lgkmcnt waits (Pst idiom)
        const int mb = m0 + wm;
        const int b = mb >> 9, s0 = mb & 511;
        const int h = nfbase >> 6;
        u16t* vdst = Vt + ((size_t)(b * NH + h) * NDK) * NS + s0;
#pragma unroll
        for (int i = 0; i < 8; ++i) {
            const int chunk = i * 64 + lane;        // 0..511
            const int dk = chunk >> 3, sg = chunk & 7;
            u16x8 v;
#pragma unroll
            for (int j = 0; j < 8; ++j) v[j] = T[(sg * 8 + j) * 72 + dk];
            *(u16x8*)&vdst[(size_t)dk * NS + sg * 8] = v;
        }
    } else {
        // ---- Q/K epilogue: +bias, q scale, bf16 scatter to [B,H,S,DK] ----
        const float* bias = (w == 0) ? bq : bk;
        u16t* outp = (w == 0) ? Qp : Kp;
        const float scale = (w == 0) ? 0.125f : 1.0f;
#pragma unroll
        for (int nt = 0; nt < 4; ++nt) {
            const int nf = nfbase + nt * 16 + cl;   // feature 0..1023
            const int h = nf >> 6, dk = nf & 63;
            const float bval = bias[nf];
#pragma unroll
            for (int mt = 0; mt < 4; ++mt) {
#pragma unroll
                for (int r = 0; r < 4; ++r) {
                    const int m = m0 + wm + mt * 16 + g4 * 4 + r;
                    const int b = m >> 9, s = m & 511;
                    float val = (acc[mt][nt][r] + bval) * scale;
                    outp[((size_t)(b * NH + h) * NS + s) * NDK + dk] = f2bf(val);
                }
            }
        }
    }
}

// ---------------------------------------------------------------------------
// Kernel 3: fused attention per (b, h, 64 q-rows). Wave owns 16 q rows.
// Pass 1: E[kt] = exp(q.k) masked, kept in 128 VGPRs; row sums via shfl_xor.
// Pass 2: normalize -> write attn; P->LDS->A-frag; PV MFMA with Vt B-frags.
// Pst is per-wave private => NO __syncthreads needed (intra-wave LDS RAW is
// ordered by compiler-inserted lgkmcnt waits).
//
// R4: reverted to the R1 E-cache structure (the R3 recompute variant was
// ~9us slower: the duplicated QK^T+exp sat on the critical path before
// every P-store). Carried: XCD-pin remap, wave-uniform length-skip,
// vectorized zero tail.
// ---------------------------------------------------------------------------
__global__ __launch_bounds__(256) void attn_kernel(
    const u16t* __restrict__ Qp, const u16t* __restrict__ Kp,
    const u16t* __restrict__ Vt, const int* __restrict__ length,
    float* __restrict__ ctx, float* __restrict__ attn)
{
    __shared__ __align__(16) u16t Pst[4][16 * 40];  // per-wave, row stride 40
    const int tid = threadIdx.x, lane = tid & 63, wave = tid >> 6;
    const int cl = lane & 15, g4 = lane >> 4;
    const int raw = blockIdx.x;          // 0..4095
    const int bh = ((raw >> 6) << 3) | (raw & 7);  // XCD-pinned: bh%8 == raw%8
    const int qt = (raw >> 3) & 7;
    const int b = bh >> 4;
    const int len = length[b];
    const int nkt = (len + 15) >> 4;     // valid 16-key groups, 1..32
    const int ng  = (len + 31) >> 5;     // valid 32-key groups, 1..16
    const int qbase = qt * 64 + wave * 16;

    const u16t* qptr = Qp + (size_t)bh * NS * NDK + (size_t)qbase * NDK;
    const u16t* kptr = Kp + (size_t)bh * NS * NDK;
    const u16t* vtptr = Vt + (size_t)bh * NDK * NS;

    // Q A-frags (dk 0..31 and 32..63); q already scaled by 1/8
    const bf16x8 aq0 = *(const bf16x8*)&qptr[cl * 64 + g4 * 8];
    const bf16x8 aq1 = *(const bf16x8*)&qptr[cl * 64 + 32 + g4 * 8];

    f32x4 E[32];
    float rs[4] = {0.f, 0.f, 0.f, 0.f};
#pragma unroll
    for (int kt = 0; kt < 32; ++kt) {
        if (kt < nkt) {                  // wave-uniform (len uniform in block)
            const bf16x8 bk0 = *(const bf16x8*)&kptr[(kt * 16 + cl) * 64 + g4 * 8];
            const bf16x8 bk1 = *(const bf16x8*)&kptr[(kt * 16 + cl) * 64 + 32 + g4 * 8];
            f32x4 sc = {0.f, 0.f, 0.f, 0.f};
            sc = __builtin_amdgcn_mfma_f32_16x16x32_bf16(aq0, bk0, sc, 0, 0, 0);
            sc = __builtin_amdgcn_mfma_f32_16x16x32_bf16(aq1, bk1, sc, 0, 0, 0);
            const bool valid = (kt * 16 + cl) < len;   // C layout: col = lane&15
            f32x4 e;
#pragma unroll
            for (int r = 0; r < 4; ++r) {
                float ev = valid ? __expf(sc[r]) : 0.0f;
                e[r] = ev;
                rs[r] += ev;
            }
            E[kt] = e;
        } else {
            E[kt] = (f32x4){0.f, 0.f, 0.f, 0.f};
        }
    }

    // row-sum reduce across the 16 lanes sharing a row group (low 4 lane bits)
#pragma unroll
    for (int r = 0; r < 4; ++r) {
        float v = rs[r];
        v += __shfl_xor(v, 1);
        v += __shfl_xor(v, 2);
        v += __shfl_xor(v, 4);
        v += __shfl_xor(v, 8);
        rs[r] = 1.0f / (v + 1e-8f);
    }

    f32x4 cacc[4] = {};
    float* attnw = attn + ((size_t)bh * NS + qbase) * NS;
#pragma unroll
    for (int g = 0; g < 16; ++g) {       // 32-key groups
        if (g < ng) {                    // wave-uniform guard
#pragma unroll
            for (int t = 0; t < 2; ++t) {
                const int kt = g * 2 + t;
#pragma unroll
                for (int r = 0; r < 4; ++r) {
                    const float a = E[kt][r] * rs[r];
                    attnw[(size_t)(g4 * 4 + r) * NS + kt * 16 + cl] = a;
                    Pst[wave][(g4 * 4 + r) * 40 + t * 16 + cl] = f2bf(a);
                }
            }
            // P A-frag: rows=q (lane&15), k=key offset g4*8..+8 within the 32
            const bf16x8 ap = *(const bf16x8*)&Pst[wave][cl * 40 + g4 * 8];
#pragma unroll
            for (int nt = 0; nt < 4; ++nt) {
                const bf16x8 bv = *(const bf16x8*)
                    &vtptr[(size_t)(nt * 16 + cl) * NS + g * 32 + g4 * 8];
                cacc[nt] = __builtin_amdgcn_mfma_f32_16x16x32_bf16(
                    ap, bv, cacc[nt], 0, 0, 0);
            }
        }
    }

    // zero tail of attn (cols >= ng*32 are exactly 0 after masking+normalize)
    {
        const int zr = lane >> 2;            // 16 rows per wave
        const int zc = (lane & 3) * 4;       // 4 float4 lanes per row
        const float4 z = {0.f, 0.f, 0.f, 0.f};
        for (int c = ng * 32; c < NS; c += 16)
            *(float4*)&attnw[(size_t)zr * NS + c + zc] = z;
    }

    // context write: [b, s, h*64+dk]
    float* cw = ctx + ((size_t)b * NS + qbase) * ND + (bh & 15) * NDK;
#pragma unroll
    for (int nt = 0; nt < 4; ++nt)
#pragma unroll
        for (int r = 0; r < 4; ++r)
            cw[(size_t)(g4 * 4 + r) * ND + nt * 16 + cl] = cacc[nt][r];
}

// ---------------------------------------------------------------------------
extern "C" void kernel_launch(void* const* d_in, const int* in_sizes, int n_in,
                              void* d_out, int out_size, void* d_ws, size_t ws_size,
                              hipStream_t stream)
{
    const float* Q   = (const float*)d_in[0];
    const float* Wq  = (const float*)d_in[1];
    const float* bq  = (const float*)d_in[2];
    const float* Wk  = (const float*)d_in[3];
    const float* bk  = (const float*)d_in[4];
    const float* Wv  = (const float*)d_in[5];
    const float* bv  = (const float*)d_in[6];
    const int* length = (const int*)d_in[7];

    float* ctx  = (float*)d_out;                     // 16,777,216 floats
    float* attn = (float*)d_out + 16777216;          // 134,217,728 floats

    char* ws = (char*)d_ws;
    const size_t szX  = 33554432;   // 16.8M bf16
    const size_t szW  = 6291456;    // 3.1M bf16
    const size_t szP  = 33554432;   // each of Qp/Kp/Vt

    u16t *X, *Wc, *Qp, *Kp, *Vt;
    const size_t needA = szX + szW + 3 * szP;        // ~140 MB
    if (ws_size >= needA) {
        X  = (u16t*)(ws);
        Wc = (u16t*)(ws + szX);
        Qp = (u16t*)(ws + szX + szW);
        Kp = (u16t*)(ws + szX + szW + szP);
        Vt = (u16t*)(ws + szX + szW + 2 * szP);
    } else {
        // fallback: stage X/Wc in the attn output region (dead before attn
        // kernel runs); qkv buffers in ws (needs ~100 MB)
        X  = (u16t*)(attn);
        Wc = (u16t*)((char*)attn + szX);
        Qp = (u16t*)(ws);
        Kp = (u16t*)(ws + szP);
        Vt = (u16t*)(ws + 2 * szP);
    }

    cast_kernel<<<dim3(2048), dim3(256), 0, stream>>>(
        (const float4*)Q, (const float4*)Wq, (const float4*)Wk,
        (const float4*)Wv, X, Wc);

    gemm_qkv<<<dim3(128, 24), dim3(256), 0, stream>>>(
        X, Wc, bq, bk, bv, Qp, Kp, Vt);

    attn_kernel<<<dim3(4096), dim3(256), 0, stream>>>(
        Qp, Kp, Vt, length, ctx, attn);
}